// Round 1
// baseline (76.805 us; speedup 1.0000x reference)
//
#include <hip/hip_runtime.h>

#define CIN    256
#define COUT   256
#define PTOT   4096
#define BN     64
#define BK     32
#define KSTEPS 8
#define LDSK   48   // padded k-stride (bf16 elems): 32 data + 16 pad, 96B rows (16B-aligned)

typedef __attribute__((ext_vector_type(8)))  short bfrag;
typedef __attribute__((ext_vector_type(16))) float f32x16;

__device__ __forceinline__ unsigned int f2bf(float f) {
    unsigned int x = __float_as_uint(f);
    x += 0x7fffu + ((x >> 16) & 1u);   // round-to-nearest-even
    return x >> 16;                    // bf16 bits in low 16
}

// XOR-swizzle the k index (bits 3..4) keyed by row bits 2..3 — applied on BOTH
// write and read sides (rule #21). Keeps 8-elem (16B) groups contiguous/aligned.
__device__ __forceinline__ int swz(int row, int k) {
    return k ^ (((row >> 2) & 3) << 3);
}

__device__ __forceinline__ f32x16 zero16() {
    f32x16 v;
    #pragma unroll
    for (int i = 0; i < 16; ++i) v[i] = 0.0f;
    return v;
}

__global__ __launch_bounds__(256, 2)
void selconv_mfma(const float* __restrict__ x,
                  const int*   __restrict__ classes,
                  const float* __restrict__ weight,
                  const float* __restrict__ bias,
                  float*       __restrict__ out)
{
    __shared__ unsigned short As[2][COUT * LDSK]; // 2 x 24576 B
    __shared__ unsigned short Bs[2][BN * LDSK];   // 2 x  6144 B
    __shared__ float bias_s[COUT];                // 1 KB   (total 62.5 KB)

    // XCD-aware swizzle: blocks of one sample land on one XCD (weight stays in L2).
    const int b     = blockIdx.x;        // 0..2047, 2048 % 8 == 0 (bijective)
    const int xcd   = b & 7;
    const int local = b >> 3;            // 0..255
    const int n     = xcd * 4 + (local >> 6); // 0..31
    const int pt    = local & 63;        // 0..63
    const int p0    = pt * BN;

    const int tid  = threadIdx.x;
    const int lane = tid & 63;
    const int wid  = tid >> 6;           // 0..3 -> o-range wid*64

    const int cls = classes[n];
    const float* Wn = weight + (size_t)cls * (COUT * CIN);
    const float* Xn = x   + (size_t)n * (CIN * PTOT) + p0;
    float*       On = out + (size_t)n * (COUT * PTOT) + p0;

    bias_s[tid] = bias[cls * COUT + tid];

    // staging thread mapping
    const int a_row0 = tid >> 3;         // 0..31, step 32 over 8 iters -> 256 rows
    const int a_col  = (tid & 7) * 4;    // 0..28 (k within BK)
    const int b_k2   = (tid >> 4) * 2;   // 0..30 (pair of k rows)
    const int b_p4   = (tid & 15) * 4;   // 0..60 (4 pixels)

    float4 av[8];
    float4 bva, bvb;

    auto load_tile = [&](int t) {
        const int k0 = t * BK;
        #pragma unroll
        for (int i = 0; i < 8; ++i)
            av[i] = *(const float4*)(Wn + (size_t)(a_row0 + 32 * i) * CIN + k0 + a_col);
        bva = *(const float4*)(Xn + (size_t)(k0 + b_k2)     * PTOT + b_p4);
        bvb = *(const float4*)(Xn + (size_t)(k0 + b_k2 + 1) * PTOT + b_p4);
    };

    auto write_tile = [&](int buf) {
        #pragma unroll
        for (int i = 0; i < 8; ++i) {
            const int row = a_row0 + 32 * i;
            uint2 w;
            w.x = f2bf(av[i].x) | (f2bf(av[i].y) << 16);
            w.y = f2bf(av[i].z) | (f2bf(av[i].w) << 16);
            *(uint2*)(&As[buf][row * LDSK + swz(row, a_col)]) = w;
        }
        const float pa[4] = {bva.x, bva.y, bva.z, bva.w};
        const float pb[4] = {bvb.x, bvb.y, bvb.z, bvb.w};
        #pragma unroll
        for (int i = 0; i < 4; ++i) {
            const int p = b_p4 + i;
            unsigned int w = f2bf(pa[i]) | (f2bf(pb[i]) << 16); // low=k2, high=k2+1
            *(unsigned int*)(&Bs[buf][p * LDSK + swz(p, b_k2)]) = w;
        }
    };

    const int fr  = lane & 31;           // row/col within 32x32 frag
    const int fg8 = (lane >> 5) * 8;     // k-group: 8 consecutive k per lane
                                         // (same mapping for A and B -> any hw k-perm cancels)
    f32x16 acc00 = zero16(), acc01 = zero16(), acc10 = zero16(), acc11 = zero16();

    load_tile(0);
    write_tile(0);
    __syncthreads();

    for (int t = 0; t < KSTEPS; ++t) {
        const int buf = t & 1;
        if (t + 1 < KSTEPS) load_tile(t + 1);   // issue next-tile global loads early

        const unsigned short* Ab = As[buf];
        const unsigned short* Bb = Bs[buf];
        const int rowA0 = wid * 64 + fr;
        #pragma unroll
        for (int s = 0; s < 2; ++s) {
            const int kof = s * 16 + fg8;
            bfrag a0 = *(const bfrag*)(&Ab[(rowA0     ) * LDSK + swz(rowA0,      kof)]);
            bfrag a1 = *(const bfrag*)(&Ab[(rowA0 + 32) * LDSK + swz(rowA0 + 32, kof)]);
            bfrag b0 = *(const bfrag*)(&Bb[(fr     ) * LDSK + swz(fr,      kof)]);
            bfrag b1 = *(const bfrag*)(&Bb[(fr + 32) * LDSK + swz(fr + 32, kof)]);
            acc00 = __builtin_amdgcn_mfma_f32_32x32x16_bf16(a0, b0, acc00, 0, 0, 0);
            acc01 = __builtin_amdgcn_mfma_f32_32x32x16_bf16(a0, b1, acc01, 0, 0, 0);
            acc10 = __builtin_amdgcn_mfma_f32_32x32x16_bf16(a1, b0, acc10, 0, 0, 0);
            acc11 = __builtin_amdgcn_mfma_f32_32x32x16_bf16(a1, b1, acc11, 0, 0, 0);
        }

        if (t + 1 < KSTEPS) write_tile(buf ^ 1); // LDS writes after MFMA (latency hidden)
        __syncthreads();
    }

    // epilogue: D col = lane&31, row = (reg&3) + 8*(reg>>2) + 4*(lane>>5)
    const int col = lane & 31;
    const int rh  = (lane >> 5) * 4;

    auto store_frag = [&](f32x16 a, int mi, int nj) {
        const int ob = wid * 64 + mi * 32;
        const int pc = nj * 32 + col;
        #pragma unroll
        for (int r = 0; r < 16; ++r) {
            const int row = (r & 3) + 8 * (r >> 2) + rh;
            const int o   = ob + row;
            On[(size_t)o * PTOT + pc] = a[r] + bias_s[o];
        }
    };
    store_frag(acc00, 0, 0);
    store_frag(acc01, 0, 1);
    store_frag(acc10, 1, 0);
    store_frag(acc11, 1, 1);
}

extern "C" void kernel_launch(void* const* d_in, const int* in_sizes, int n_in,
                              void* d_out, int out_size, void* d_ws, size_t ws_size,
                              hipStream_t stream) {
    const float* x       = (const float*)d_in[0];
    const int*   classes = (const int*)d_in[1];
    const float* weight  = (const float*)d_in[2];
    const float* bias    = (const float*)d_in[3];
    float*       out     = (float*)d_out;

    const int grid = 32 * (PTOT / BN);   // 2048 blocks
    selconv_mfma<<<grid, 256, 0, stream>>>(x, classes, weight, bias, out);
}

// Round 2
// 62.830 us; speedup vs baseline: 1.2224x; 1.2224x over previous
//
#include <hip/hip_runtime.h>

#define CIN    256
#define COUT   256
#define PTOT   4096
#define BM     128
#define BN     128
#define BK     32
#define KSTEPS 8
#define LDSK   48   // padded k-stride (bf16 elems): 32 data + 16 pad -> 96B rows

typedef __attribute__((ext_vector_type(8)))  short bfrag;
typedef __attribute__((ext_vector_type(16))) float f32x16;

__device__ __forceinline__ unsigned int f2bf(float f) {
    unsigned int x = __float_as_uint(f);
    x += 0x7fffu + ((x >> 16) & 1u);   // round-to-nearest-even
    return x >> 16;
}

// XOR-swizzle k bits 3..4 keyed by row bits 2..3 — applied on BOTH write and
// read sides (rule #21). Keeps 8-elem (16B) groups contiguous/aligned; gives
// 8 distinct bank-starts within each 8-row group for ds_read_b128.
__device__ __forceinline__ int swz(int row, int k) {
    return k ^ (((row >> 2) & 3) << 3);
}

__device__ __forceinline__ f32x16 zero16() {
    f32x16 v;
    #pragma unroll
    for (int i = 0; i < 16; ++i) v[i] = 0.0f;
    return v;
}

__global__ __launch_bounds__(256, 3)
void selconv_mfma(const float* __restrict__ x,
                  const int*   __restrict__ classes,
                  const float* __restrict__ weight,
                  const float* __restrict__ bias,
                  float*       __restrict__ out)
{
    __shared__ unsigned short As[2][BM * LDSK]; // 2 x 12288 B -> 24576
    __shared__ unsigned short Bs[2][BN * LDSK]; // 2 x 12288 B -> 24576
    __shared__ float bias_s[BM];                // 512 B  (total 49664 B -> 3 blocks/CU)

    // XCD-aware bijective swizzle: 2048 % 8 == 0. Each XCD works one sample at
    // a time (weight + x slice stay in its L2).
    const int b     = blockIdx.x;
    const int xcd   = b & 7;
    const int local = b >> 3;                 // 0..255
    const int n     = xcd * 4 + (local >> 6); // 0..31
    const int rem   = local & 63;
    const int o0    = (rem >> 5) * BM;        // 0 or 128
    const int p0    = (rem & 31) * BN;        // pixel tile

    const int tid  = threadIdx.x;
    const int lane = tid & 63;
    const int wid  = tid >> 6;                // 4 waves: 2x2 output grid
    const int wr   = wid >> 1;                // o-half within BM
    const int wc   = wid & 1;                 // p-half within BN

    const int cls = classes[n];
    const float* Wn = weight + (size_t)cls * (COUT * CIN) + (size_t)o0 * CIN;
    const float* Xn = x   + (size_t)n * (CIN * PTOT) + p0;
    float*       On = out + (size_t)n * (COUT * PTOT) + (size_t)o0 * PTOT + p0;

    if (tid < BM) bias_s[tid] = bias[cls * COUT + o0 + tid];

    // staging maps
    const int a_row0 = tid >> 3;          // 0..31 (+32*i, i=0..3) -> 128 rows
    const int a_col  = (tid & 7) * 4;     // k offset within BK
    const int b_p4   = (tid & 31) * 4;    // 4 pixels, 32 lanes cover 128
    const int b_kp   = (tid >> 5) * 2;    // 0,2,..,14 ; +16*j over 2 iters

    float4 A0[4], A1[4];                  // two named prefetch sets (rule #20)
    float4 B0[4], B1[4];

    auto loadA = [&](float4 (&A)[4], int t) {
        const int k0 = t * BK;
        #pragma unroll
        for (int i = 0; i < 4; ++i)
            A[i] = *(const float4*)(Wn + (size_t)(a_row0 + 32 * i) * CIN + k0 + a_col);
    };
    auto loadB = [&](float4 (&B)[4], int t) {
        const int k0 = t * BK;
        #pragma unroll
        for (int j = 0; j < 2; ++j) {
            const int kr = k0 + b_kp + 16 * j;
            B[j * 2 + 0] = *(const float4*)(Xn + (size_t)kr       * PTOT + b_p4);
            B[j * 2 + 1] = *(const float4*)(Xn + (size_t)(kr + 1) * PTOT + b_p4);
        }
    };
    auto writeT = [&](int buf, float4 (&A)[4], float4 (&B)[4]) {
        #pragma unroll
        for (int i = 0; i < 4; ++i) {
            const int row = a_row0 + 32 * i;
            uint2 w;
            w.x = f2bf(A[i].x) | (f2bf(A[i].y) << 16);
            w.y = f2bf(A[i].z) | (f2bf(A[i].w) << 16);
            *(uint2*)(&As[buf][row * LDSK + swz(row, a_col)]) = w;
        }
        #pragma unroll
        for (int j = 0; j < 2; ++j) {
            const int kk = b_kp + 16 * j;
            const float pa[4] = {B[j*2+0].x, B[j*2+0].y, B[j*2+0].z, B[j*2+0].w};
            const float pb[4] = {B[j*2+1].x, B[j*2+1].y, B[j*2+1].z, B[j*2+1].w};
            #pragma unroll
            for (int i = 0; i < 4; ++i) {
                const int p = b_p4 + i;
                const unsigned int w = f2bf(pa[i]) | (f2bf(pb[i]) << 16); // low=kk, high=kk+1
                *(unsigned int*)(&Bs[buf][p * LDSK + swz(p, kk)]) = w;
            }
        }
    };

    const int fr  = lane & 31;            // row/col within 32x32 frag
    const int fg8 = (lane >> 5) * 8;      // 8 consecutive k per lane; identical
                                          // mapping for A and B -> k-perm cancels
    f32x16 acc00 = zero16(), acc01 = zero16(), acc10 = zero16(), acc11 = zero16();

    auto mfma_step = [&](int buf) {
        const unsigned short* Ab = As[buf];
        const unsigned short* Bb = Bs[buf];
        const int rowA0 = wr * 64 + fr;
        const int colB0 = wc * 64 + fr;
        #pragma unroll
        for (int s = 0; s < 2; ++s) {
            const int kof = s * 16 + fg8;
            bfrag a0 = *(const bfrag*)(&Ab[(rowA0     ) * LDSK + swz(rowA0,      kof)]);
            bfrag a1 = *(const bfrag*)(&Ab[(rowA0 + 32) * LDSK + swz(rowA0 + 32, kof)]);
            bfrag b0 = *(const bfrag*)(&Bb[(colB0     ) * LDSK + swz(colB0,      kof)]);
            bfrag b1 = *(const bfrag*)(&Bb[(colB0 + 32) * LDSK + swz(colB0 + 32, kof)]);
            acc00 = __builtin_amdgcn_mfma_f32_32x32x16_bf16(a0, b0, acc00, 0, 0, 0);
            acc01 = __builtin_amdgcn_mfma_f32_32x32x16_bf16(a0, b1, acc01, 0, 0, 0);
            acc10 = __builtin_amdgcn_mfma_f32_32x32x16_bf16(a1, b0, acc10, 0, 0, 0);
            acc11 = __builtin_amdgcn_mfma_f32_32x32x16_bf16(a1, b1, acc11, 0, 0, 0);
        }
    };

    // ---- 2-deep pipeline: loads for t+2 issued at step t ----
    loadA(A0, 0); loadB(B0, 0);
    loadA(A1, 1); loadB(B1, 1);
    writeT(0, A0, B0);
    __syncthreads();

    #pragma unroll
    for (int t = 0; t < KSTEPS; t += 2) {
        if (t + 2 < KSTEPS) { loadA(A0, t + 2); loadB(B0, t + 2); }
        mfma_step(0);
        writeT(1, A1, B1);                 // tile t+1 (regs loaded one step ago)
        __syncthreads();
        if (t + 3 < KSTEPS) { loadA(A1, t + 3); loadB(B1, t + 3); }
        mfma_step(1);
        if (t + 2 < KSTEPS) { writeT(0, A0, B0); __syncthreads(); }
    }

    // epilogue: D col = lane&31, row = (reg&3) + 8*(reg>>2) + 4*(lane>>5)
    const int col = lane & 31;
    const int rh  = (lane >> 5) * 4;

    auto store_frag = [&](f32x16 a, int mi, int nj) {
        const int ob = wr * 64 + mi * 32;
        const int pc = wc * 64 + nj * 32 + col;
        #pragma unroll
        for (int r = 0; r < 16; ++r) {
            const int row = (r & 3) + 8 * (r >> 2) + rh;
            const int o   = ob + row;
            On[(size_t)o * PTOT + pc] = a[r] + bias_s[o];
        }
    };
    store_frag(acc00, 0, 0);
    store_frag(acc01, 0, 1);
    store_frag(acc10, 1, 0);
    store_frag(acc11, 1, 1);
}

extern "C" void kernel_launch(void* const* d_in, const int* in_sizes, int n_in,
                              void* d_out, int out_size, void* d_ws, size_t ws_size,
                              hipStream_t stream) {
    const float* x       = (const float*)d_in[0];
    const int*   classes = (const int*)d_in[1];
    const float* weight  = (const float*)d_in[2];
    const float* bias    = (const float*)d_in[3];
    float*       out     = (float*)d_out;

    const int grid = 32 * (COUT / BM) * (PTOT / BN);  // 32*2*32 = 2048
    selconv_mfma<<<grid, 256, 0, stream>>>(x, classes, weight, bias, out);
}